// Round 7
// baseline (90.507 us; speedup 1.0000x reference)
//
#include <hip/hip_runtime.h>
#include <hip/hip_bf16.h>

#define NUM_CLASS 21
#define IGNORE_L 255
#define EPSF 1e-6f
// Problem dims (fixed by setup_inputs): B=8, D=512, H=W=128 -> HW=16384
#define BATCH 8
#define DCH 512
#define HW 16384
#define NROWS (BATCH * DCH)   // 4096 scatter blocks

__device__ __forceinline__ float waveReduce(float v) {
    #pragma unroll
    for (int m = 1; m < 64; m <<= 1) v += __shfl_xor(v, m, 64);
    return v;
}

// Batched LDS RMW for one float4 + 4 packed u8 labels. Slot rotation
// s0..s3 = (lane+16k)&63 makes the 4 addresses mutually distinct BY
// CONSTRUCTION, so R,R,R,R / add*4 / W,W,W,W is safe (one lgkmcnt stall per
// 4 elements). Invalid labels clamp to class 0 with a gated +0 (branchless).
// ss += g*f = f*f for valid elements, 0 otherwise.
__device__ __forceinline__ void rmw4p(float* __restrict__ smw,
                                      int s0, int s1, int s2, int s3,
                                      float4 f, unsigned lw, float& ss) {
    const int c0 =  lw        & 255;
    const int c1 = (lw >> 8)  & 255;
    const int c2 = (lw >> 16) & 255;
    const int c3 =  lw >> 24;
    const bool b0 = c0 < NUM_CLASS;
    const bool b1 = c1 < NUM_CLASS;
    const bool b2 = c2 < NUM_CLASS;
    const bool b3 = c3 < NUM_CLASS;
    const int a0 = (b0 ? c0 : 0) * 64 + s0;
    const int a1 = (b1 ? c1 : 0) * 64 + s1;
    const int a2 = (b2 ? c2 : 0) * 64 + s2;
    const int a3 = (b3 ? c3 : 0) * 64 + s3;
    const float g0 = b0 ? f.x : 0.0f;
    const float g1 = b1 ? f.y : 0.0f;
    const float g2 = b2 ? f.z : 0.0f;
    const float g3 = b3 ? f.w : 0.0f;
    const float t0 = smw[a0];
    const float t1 = smw[a1];
    const float t2 = smw[a2];
    const float t3 = smw[a3];
    smw[a0] = t0 + g0;
    smw[a1] = t1 + g1;
    smw[a2] = t2 + g2;
    smw[a3] = t3 + g3;
    ss = fmaf(g0, f.x, ss);
    ss = fmaf(g1, f.y, ss);
    ss = fmaf(g2, f.z, ss);
    ss = fmaf(g3, f.w, ss);
}

// ---------------------------------------------------------------------------
// Label pack: int32 labels -> u8 (4 labels per u32). 512KB -> 128KB once;
// scatter blocks then read 16KB instead of 64KB of labels per row.
// ---------------------------------------------------------------------------
__global__ __launch_bounds__(256) void car_pack_kernel(
    const int* __restrict__ label, unsigned* __restrict__ packed)
{
    const int idx = blockIdx.x * 256 + threadIdx.x;   // 32768 outputs
    int4 l = ((const int4*)label)[idx];
    packed[idx] = (unsigned)(l.x & 255) | ((unsigned)(l.y & 255) << 8) |
                  ((unsigned)(l.z & 255) << 16) | ((unsigned)(l.w & 255) << 24);
}

// ---------------------------------------------------------------------------
// Fused kernel: blocks [0,8) do per-batch counts; blocks [8, 8+NROWS) do the
// per-(b,d) row segmented class sums + sum-of-squares partials.
// Per-wave private LDS copies (no atomics; gfx950 ds_add_f32 is ~lane-serial).
// Slim body (<=64 VGPR via launch_bounds) -> ~28 waves/CU so TLP hides HBM
// and LDS latency; compiler hoists next-iter loads (no LDS/global aliasing).
// ---------------------------------------------------------------------------
__global__ __launch_bounds__(256, 8) void car_fused_kernel(
    const float* __restrict__ features, const unsigned* __restrict__ plabel,
    float* __restrict__ class_sum, float* __restrict__ ss_parts,
    float* __restrict__ counts, float* __restrict__ total_parts)
{
    __shared__ float sm[4][NUM_CLASS * 64];
    __shared__ float red[4];
    const int t = threadIdx.x;
    const int lane = t & 63;
    const int wave = t >> 6;
    const int s0 = lane;
    const int s1 = (lane + 16) & 63;
    const int s2 = (lane + 32) & 63;
    const int s3 = (lane + 48) & 63;

    float* __restrict__ smw = &sm[wave][0];
    #pragma unroll
    for (int i = lane; i < NUM_CLASS * 64; i += 64) smw[i] = 0.0f;
    // no sync needed: each wave touches only its own copy until the merge

    if (blockIdx.x < BATCH) {
        // ---- counts path: same machinery with f = (1,1,1,1); ss == count ----
        const int b = blockIdx.x;
        const unsigned* __restrict__ plrow = plabel + (size_t)b * (HW / 4);
        const float4 f1 = {1.f, 1.f, 1.f, 1.f};
        float tv = 0.0f;
        #pragma unroll 2
        for (int i = 0; i < 16; ++i) {
            unsigned lw = plrow[i * 256 + t];
            rmw4p(smw, s0, s1, s2, s3, f1, lw, tv);
        }
        __syncthreads();
        for (int c = wave; c < NUM_CLASS; c += 4) {
            const int idx = c * 64 + lane;
            float v = sm[0][idx] + sm[1][idx] + sm[2][idx] + sm[3][idx];
            v = waveReduce(v);
            if (lane == 0) counts[b * NUM_CLASS + c] = v;
        }
        tv = waveReduce(tv);
        if (lane == 0) red[wave] = tv;
        __syncthreads();
        if (t == 0) total_parts[b] = red[0] + red[1] + red[2] + red[3];
        return;
    }

    // ---- scatter path ----
    const int row = blockIdx.x - BATCH;   // b*512 + d
    const int b = row >> 9;
    const int d = row & 511;

    const float4* __restrict__ frow = (const float4*)(features + (size_t)row * HW);
    const unsigned* __restrict__ plrow = plabel + (size_t)b * (HW / 4);

    float ss = 0.0f;
    #pragma unroll 2
    for (int i = 0; i < 16; ++i) {
        float4   f = frow[i * 256 + t];
        unsigned lw = plrow[i * 256 + t];
        rmw4p(smw, s0, s1, s2, s3, f, lw, ss);
    }
    __syncthreads();

    // Merge 4 wave-copies, reduce 64 slots per class (rotation-invariant).
    float* __restrict__ out_row = class_sum + (size_t)b * NUM_CLASS * DCH + d;
    for (int c = wave; c < NUM_CLASS; c += 4) {
        const int idx = c * 64 + lane;
        float v = sm[0][idx] + sm[1][idx] + sm[2][idx] + sm[3][idx];
        v = waveReduce(v);
        if (lane == 0) out_row[(size_t)c * DCH] = v;
    }

    ss = waveReduce(ss);
    if (lane == 0) red[wave] = ss;
    __syncthreads();
    if (t == 0) ss_parts[row] = red[0] + red[1] + red[2] + red[3];
}

// ---------------------------------------------------------------------------
// Finalize (1 block, 512 threads).
//  0: sum ss_parts[4096].
//  A: centers, intra correction  corr = sum cen*(n*cen - 2S); batch-mean cm.
//  C: per-class norms of cm.   D: 21x21 cosine sim -> inter loss.
//  out[0] = (ss + corr)/(total+eps); out[1] = sum relu(sim-.5)/(21+eps).
// ---------------------------------------------------------------------------
__global__ __launch_bounds__(512) void car_finalize_kernel(
    const float* __restrict__ class_sum, const float* __restrict__ counts,
    const float* __restrict__ ss_parts, const float* __restrict__ total_parts,
    float* __restrict__ out)
{
    __shared__ float cm[NUM_CLASS * DCH];
    __shared__ float norms[NUM_CLASS];
    __shared__ float redC[8];
    __shared__ float redS[8];
    __shared__ float redB[8];
    const int t = threadIdx.x;
    const int lane = t & 63;
    const int wave = t >> 6;

    float ssp = 0.0f;
    #pragma unroll
    for (int i = 0; i < NROWS / 512; ++i) ssp += ss_parts[i * 512 + t];

    float corr = 0.0f;
    for (int p = t; p < NUM_CLASS * DCH; p += 512) {
        const int c = p >> 9;
        float s = 0.0f;
        #pragma unroll
        for (int b = 0; b < BATCH; ++b) {
            float S = class_sum[(size_t)b * NUM_CLASS * DCH + p];
            float n = counts[b * NUM_CLASS + c];
            float cen = S / (n + EPSF);
            corr += cen * (n * cen - 2.0f * S);
            s += cen;
        }
        cm[p] = s * (1.0f / BATCH);
    }
    corr = waveReduce(corr);
    ssp  = waveReduce(ssp);
    if (lane == 0) { redC[wave] = corr; redS[wave] = ssp; }
    __syncthreads();

    for (int c = wave; c < NUM_CLASS; c += 8) {
        float s = 0.0f;
        #pragma unroll
        for (int k = 0; k < DCH / 64; ++k) {
            float v = cm[c * DCH + k * 64 + lane];
            s += v * v;
        }
        s = waveReduce(s);
        if (lane == 0) norms[c] = fmaxf(sqrtf(s), 1e-12f);
    }
    __syncthreads();

    float interAcc = 0.0f;
    for (int p = wave; p < NUM_CLASS * NUM_CLASS; p += 8) {
        const int c1 = p / NUM_CLASS;
        const int c2 = p % NUM_CLASS;
        if (c1 == c2) continue;
        float s = 0.0f;
        #pragma unroll
        for (int k = 0; k < DCH / 64; ++k)
            s += cm[c1 * DCH + k * 64 + lane] * cm[c2 * DCH + k * 64 + lane];
        s = waveReduce(s);
        if (lane == 0) {
            float sim = s / (norms[c1] * norms[c2]);
            interAcc += fmaxf(sim - 0.5f, 0.0f);
        }
    }
    if (lane == 0) redB[wave] = interAcc;
    __syncthreads();

    if (t == 0) {
        float corrT = 0.0f, interT = 0.0f, ssT = 0.0f, tot = 0.0f;
        #pragma unroll
        for (int w = 0; w < 8; ++w) { corrT += redC[w]; interT += redB[w]; ssT += redS[w]; }
        #pragma unroll
        for (int b = 0; b < BATCH; ++b) tot += total_parts[b];
        out[0] = (ssT + corrT) / (tot + EPSF);
        out[1] = interT / ((float)NUM_CLASS + EPSF);
    }
}

extern "C" void kernel_launch(void* const* d_in, const int* in_sizes, int n_in,
                              void* d_out, int out_size, void* d_ws, size_t ws_size,
                              hipStream_t stream) {
    const float* features = (const float*)d_in[0];
    const int*   label    = (const int*)d_in[1];
    float* out = (float*)d_out;

    // ws layout (floats):
    //   [0 .. 4096)          ss_parts
    //   [4096 .. 4104)       total_parts
    //   [4104 .. 4272)       counts (8*21)
    //   [4352 .. 90368)      class_sum[8][21][512]
    //   [90368 .. 123136)    packed u8 labels (131072 bytes)
    float* ws          = (float*)d_ws;
    float* ss_parts    = ws + 0;
    float* total_parts = ws + 4096;
    float* counts      = ws + 4104;
    float* class_sum   = ws + 4352;
    unsigned* plabel   = (unsigned*)(ws + 90368);

    car_pack_kernel<<<(BATCH * HW) / (4 * 256), 256, 0, stream>>>(label, plabel);
    car_fused_kernel<<<NROWS + BATCH, 256, 0, stream>>>(
        features, plabel, class_sum, ss_parts, counts, total_parts);
    car_finalize_kernel<<<1, 512, 0, stream>>>(class_sum, counts, ss_parts, total_parts, out);
}

// Round 8
// 77.349 us; speedup vs baseline: 1.1701x; 1.1701x over previous
//
#include <hip/hip_runtime.h>
#include <hip/hip_bf16.h>

#define NUM_CLASS 21
#define IGNORE_L 255
#define EPSF 1e-6f
// Problem dims (fixed by setup_inputs): B=8, D=512, H=W=128 -> HW=16384
#define BATCH 8
#define DCH 512
#define HW 16384
#define NPAIRS (BATCH * DCH / 2)   // 2048 scatter blocks (one per d-pair)

__device__ __forceinline__ float waveReduce(float v) {
    #pragma unroll
    for (int m = 1; m < 64; m <<= 1) v += __shfl_xor(v, m, 64);
    return v;
}

// Per-element float2 LDS RMW (rows d0,d0+1 packed in one b64 slot).
// R and W adjacent per element; within one element step the 64 lanes hit
// distinct addresses (slot = (lane+16k)&63, same k), so the step is
// race-free; steps are ordered by the wave's in-order DS execution.
// Invalid labels clamp to class 0 with gated +0. ss accumulates f^2 for
// both rows (valid elements only).
__device__ __forceinline__ void rmwq(float2* __restrict__ smw,
                                     int s0, int s1, int s2, int s3,
                                     float4 fa, float4 fb, int4 l, float& ss) {
    {
        const bool v = (unsigned)l.x < NUM_CLASS;
        const int a = (v ? l.x : 0) * 64 + s0;
        const float ga = v ? fa.x : 0.0f, gb = v ? fb.x : 0.0f;
        float2 w = smw[a]; w.x += ga; w.y += gb; smw[a] = w;
        ss = fmaf(ga, fa.x, ss); ss = fmaf(gb, fb.x, ss);
    }
    {
        const bool v = (unsigned)l.y < NUM_CLASS;
        const int a = (v ? l.y : 0) * 64 + s1;
        const float ga = v ? fa.y : 0.0f, gb = v ? fb.y : 0.0f;
        float2 w = smw[a]; w.x += ga; w.y += gb; smw[a] = w;
        ss = fmaf(ga, fa.y, ss); ss = fmaf(gb, fb.y, ss);
    }
    {
        const bool v = (unsigned)l.z < NUM_CLASS;
        const int a = (v ? l.z : 0) * 64 + s2;
        const float ga = v ? fa.z : 0.0f, gb = v ? fb.z : 0.0f;
        float2 w = smw[a]; w.x += ga; w.y += gb; smw[a] = w;
        ss = fmaf(ga, fa.z, ss); ss = fmaf(gb, fb.z, ss);
    }
    {
        const bool v = (unsigned)l.w < NUM_CLASS;
        const int a = (v ? l.w : 0) * 64 + s3;
        const float ga = v ? fa.w : 0.0f, gb = v ? fb.w : 0.0f;
        float2 w = smw[a]; w.x += ga; w.y += gb; smw[a] = w;
        ss = fmaf(ga, fa.w, ss); ss = fmaf(gb, fb.w, ss);
    }
}

// ---------------------------------------------------------------------------
// Fused kernel: blocks [0,8) per-batch counts; blocks [8, 8+NPAIRS) handle a
// (b, d0=2*pair) ROW PAIR: labels read once per pair (halves label traffic),
// float2 slots halve DS instruction count vs one-row blocks.
// Per-wave private LDS copies (no atomics; gfx950 ds_add_f32 ~lane-serial).
// 4-deep prefetch ring covers HBM latency at 3 blocks/CU occupancy.
// ---------------------------------------------------------------------------
__global__ __launch_bounds__(256) void car_fused_kernel(
    const float* __restrict__ features, const int* __restrict__ label,
    float* __restrict__ class_sum, float* __restrict__ ss_parts,
    float* __restrict__ counts, float* __restrict__ total_parts)
{
    __shared__ float2 sm[4][NUM_CLASS * 64];
    __shared__ float red[4];
    const int t = threadIdx.x;
    const int lane = t & 63;
    const int wave = t >> 6;
    const int s0 = lane;
    const int s1 = (lane + 16) & 63;
    const int s2 = (lane + 32) & 63;
    const int s3 = (lane + 48) & 63;

    float2* __restrict__ smw = &sm[wave][0];
    #pragma unroll
    for (int i = lane; i < NUM_CLASS * 64; i += 64) smw[i] = make_float2(0.f, 0.f);
    // no sync: each wave touches only its own copy until the merge

    if (blockIdx.x < BATCH) {
        // ---- counts path: fa = ones, fb = 0; slot .x accumulates count ----
        const int b = blockIdx.x;
        const int4* __restrict__ lrow = (const int4*)(label + (size_t)b * HW);
        const float4 f1 = {1.f, 1.f, 1.f, 1.f};
        const float4 f0 = {0.f, 0.f, 0.f, 0.f};
        float tv = 0.0f;
        #pragma unroll 2
        for (int i = 0; i < 16; ++i) {
            int4 l = lrow[i * 256 + t];
            rmwq(smw, s0, s1, s2, s3, f1, f0, l, tv);  // tv += 1 per valid
        }
        __syncthreads();
        for (int c = wave; c < NUM_CLASS; c += 4) {
            const float4 vA = *(const float4*)((const float*)&sm[lane >> 5][c * 64] + (lane & 31) * 4);
            const float4 vB = *(const float4*)((const float*)&sm[2 + (lane >> 5)][c * 64] + (lane & 31) * 4);
            float px = (vA.x + vA.z) + (vB.x + vB.z);
            px = waveReduce(px);
            if (lane == 0) counts[b * NUM_CLASS + c] = px;
        }
        tv = waveReduce(tv);
        if (lane == 0) red[wave] = tv;
        __syncthreads();
        if (t == 0) total_parts[b] = red[0] + red[1] + red[2] + red[3];
        return;
    }

    // ---- scatter path: row pair (b, d0), (b, d0+1) ----
    const int r = blockIdx.x - BATCH;          // 0..NPAIRS-1
    const int b = r >> 8;
    const int d0 = (r & 255) * 2;
    const float4* __restrict__ frow0 = (const float4*)(features + ((size_t)b * DCH + d0) * HW);
    const float4* __restrict__ frow1 = (const float4*)(features + ((size_t)b * DCH + d0 + 1) * HW);
    const int4* __restrict__ lrow = (const int4*)(label + (size_t)b * HW);

    // 4-deep prefetch ring (named regs; runtime-indexed arrays would spill).
    float4 A0 = frow0[0 * 256 + t], B0 = frow1[0 * 256 + t];
    float4 A1 = frow0[1 * 256 + t], B1 = frow1[1 * 256 + t];
    float4 A2 = frow0[2 * 256 + t], B2 = frow1[2 * 256 + t];
    float4 A3 = frow0[3 * 256 + t], B3 = frow1[3 * 256 + t];
    int4 L0 = lrow[0 * 256 + t], L1 = lrow[1 * 256 + t];
    int4 L2 = lrow[2 * 256 + t], L3 = lrow[3 * 256 + t];
    float ss = 0.0f;

    #pragma unroll 1
    for (int i = 0; i < 12; i += 4) {
        rmwq(smw, s0, s1, s2, s3, A0, B0, L0, ss);
        A0 = frow0[(i + 4) * 256 + t]; B0 = frow1[(i + 4) * 256 + t]; L0 = lrow[(i + 4) * 256 + t];
        rmwq(smw, s0, s1, s2, s3, A1, B1, L1, ss);
        A1 = frow0[(i + 5) * 256 + t]; B1 = frow1[(i + 5) * 256 + t]; L1 = lrow[(i + 5) * 256 + t];
        rmwq(smw, s0, s1, s2, s3, A2, B2, L2, ss);
        A2 = frow0[(i + 6) * 256 + t]; B2 = frow1[(i + 6) * 256 + t]; L2 = lrow[(i + 6) * 256 + t];
        rmwq(smw, s0, s1, s2, s3, A3, B3, L3, ss);
        A3 = frow0[(i + 7) * 256 + t]; B3 = frow1[(i + 7) * 256 + t]; L3 = lrow[(i + 7) * 256 + t];
    }
    rmwq(smw, s0, s1, s2, s3, A0, B0, L0, ss);
    rmwq(smw, s0, s1, s2, s3, A1, B1, L1, ss);
    rmwq(smw, s0, s1, s2, s3, A2, B2, L2, ss);
    rmwq(smw, s0, s1, s2, s3, A3, B3, L3, ss);
    __syncthreads();

    // Merge 4 wave-copies x 64 slots per class (rotation-invariant).
    // Two b128 reads/class cover all 4 copies; .x/.z = row d0, .y/.w = d0+1.
    float* __restrict__ out_base = class_sum + (size_t)b * NUM_CLASS * DCH + d0;
    for (int c = wave; c < NUM_CLASS; c += 4) {
        const float4 vA = *(const float4*)((const float*)&sm[lane >> 5][c * 64] + (lane & 31) * 4);
        const float4 vB = *(const float4*)((const float*)&sm[2 + (lane >> 5)][c * 64] + (lane & 31) * 4);
        float px = (vA.x + vA.z) + (vB.x + vB.z);
        float py = (vA.y + vA.w) + (vB.y + vB.w);
        #pragma unroll
        for (int m = 1; m < 64; m <<= 1) {
            px += __shfl_xor(px, m, 64);
            py += __shfl_xor(py, m, 64);
        }
        if (lane == 0) *(float2*)&out_base[(size_t)c * DCH] = make_float2(px, py);
    }

    ss = waveReduce(ss);
    if (lane == 0) red[wave] = ss;
    __syncthreads();
    if (t == 0) ss_parts[r] = red[0] + red[1] + red[2] + red[3];
}

// ---------------------------------------------------------------------------
// Finalize (1 block, 1024 threads / 16 waves).
//  0: sum ss_parts[2048].
//  A: centers, intra correction corr = sum cen*(n*cen - 2S); batch-mean cm.
//  C: per-class norms of cm.   D: 21x21 cosine sim -> inter loss.
//  out[0] = (ss + corr)/(total+eps); out[1] = sum relu(sim-.5)/(21+eps).
// ---------------------------------------------------------------------------
__global__ __launch_bounds__(1024) void car_finalize_kernel(
    const float* __restrict__ class_sum, const float* __restrict__ counts,
    const float* __restrict__ ss_parts, const float* __restrict__ total_parts,
    float* __restrict__ out)
{
    __shared__ float cm[NUM_CLASS * DCH];
    __shared__ float norms[NUM_CLASS];
    __shared__ float redC[16];
    __shared__ float redS[16];
    __shared__ float redB[16];
    const int t = threadIdx.x;
    const int lane = t & 63;
    const int wave = t >> 6;

    float ssp = 0.0f;
    #pragma unroll
    for (int i = 0; i < NPAIRS / 1024; ++i) ssp += ss_parts[i * 1024 + t];

    float corr = 0.0f;
    for (int p = t; p < NUM_CLASS * DCH; p += 1024) {
        const int c = p >> 9;
        float s = 0.0f;
        #pragma unroll
        for (int b = 0; b < BATCH; ++b) {
            float S = class_sum[(size_t)b * NUM_CLASS * DCH + p];
            float n = counts[b * NUM_CLASS + c];
            float cen = S / (n + EPSF);
            corr += cen * (n * cen - 2.0f * S);
            s += cen;
        }
        cm[p] = s * (1.0f / BATCH);
    }
    corr = waveReduce(corr);
    ssp  = waveReduce(ssp);
    if (lane == 0) { redC[wave] = corr; redS[wave] = ssp; }
    __syncthreads();

    for (int c = wave; c < NUM_CLASS; c += 16) {
        float s = 0.0f;
        #pragma unroll
        for (int k = 0; k < DCH / 64; ++k) {
            float v = cm[c * DCH + k * 64 + lane];
            s += v * v;
        }
        s = waveReduce(s);
        if (lane == 0) norms[c] = fmaxf(sqrtf(s), 1e-12f);
    }
    __syncthreads();

    float interAcc = 0.0f;
    for (int p = wave; p < NUM_CLASS * NUM_CLASS; p += 16) {
        const int c1 = p / NUM_CLASS;
        const int c2 = p % NUM_CLASS;
        if (c1 == c2) continue;
        float s = 0.0f;
        #pragma unroll
        for (int k = 0; k < DCH / 64; ++k)
            s += cm[c1 * DCH + k * 64 + lane] * cm[c2 * DCH + k * 64 + lane];
        s = waveReduce(s);
        if (lane == 0) {
            float sim = s / (norms[c1] * norms[c2]);
            interAcc += fmaxf(sim - 0.5f, 0.0f);
        }
    }
    if (lane == 0) redB[wave] = interAcc;
    __syncthreads();

    if (t == 0) {
        float corrT = 0.0f, interT = 0.0f, ssT = 0.0f, tot = 0.0f;
        #pragma unroll
        for (int w = 0; w < 16; ++w) { corrT += redC[w]; interT += redB[w]; ssT += redS[w]; }
        #pragma unroll
        for (int b = 0; b < BATCH; ++b) tot += total_parts[b];
        out[0] = (ssT + corrT) / (tot + EPSF);
        out[1] = interT / ((float)NUM_CLASS + EPSF);
    }
}

extern "C" void kernel_launch(void* const* d_in, const int* in_sizes, int n_in,
                              void* d_out, int out_size, void* d_ws, size_t ws_size,
                              hipStream_t stream) {
    const float* features = (const float*)d_in[0];
    const int*   label    = (const int*)d_in[1];
    float* out = (float*)d_out;

    // ws layout (floats):
    //   [0 .. 2048)          ss_parts (one per scatter block)
    //   [2048 .. 2056)       total_parts
    //   [2056 .. 2224)       counts (8*21)
    //   [2304 .. 88320)      class_sum[8][21][512]
    float* ws          = (float*)d_ws;
    float* ss_parts    = ws + 0;
    float* total_parts = ws + 2048;
    float* counts      = ws + 2056;
    float* class_sum   = ws + 2304;

    car_fused_kernel<<<NPAIRS + BATCH, 256, 0, stream>>>(
        features, label, class_sum, ss_parts, counts, total_parts);
    car_finalize_kernel<<<1, 1024, 0, stream>>>(class_sum, counts, ss_parts, total_parts, out);
}